// Round 1
// baseline (58097.803 us; speedup 1.0000x reference)
//
#include <hip/hip_runtime.h>
#include <math.h>

#define BB 32
#define TT 2048
#define FF 128
#define HH 512
#define FCC 128

// One workgroup per batch element. 1024 threads: 2 threads per hidden row
// (each handles half the 512 columns of W_hh and half the 128 cols of W_ih).
// h lives in LDS; W_hh/W_ih stream from L2 every step (baseline — known cost).
__launch_bounds__(1024, 1)
__global__ void rnn_encoder_kernel(const float* __restrict__ x,
                                   const int* __restrict__ lengths,
                                   const float* __restrict__ W_ih,
                                   const float* __restrict__ W_hh,
                                   const float* __restrict__ b_ih,
                                   const float* __restrict__ b_hh,
                                   const float* __restrict__ W1,
                                   const float* __restrict__ b1,
                                   const float* __restrict__ W2,
                                   const float* __restrict__ b2,
                                   float* __restrict__ out)
{
    __shared__ float h[HH];      // hidden state
    __shared__ float xt[FF];     // current timestep input
    __shared__ float wv[HH];     // fused scorer vector w = W2 @ W1  (shape [H])
    __shared__ float bias[HH];   // b_ih + b_hh
    __shared__ float red[16];    // per-wave reduction scratch

    const int b   = blockIdx.x;
    const int tid = threadIdx.x;
    const int len = lengths[b];

    // ---- one-time per-WG setup: h=0, fused bias, fused scorer vector ----
    if (tid < HH) {
        h[tid]    = 0.0f;
        bias[tid] = b_ih[tid] + b_hh[tid];
        float acc = 0.0f;
        #pragma unroll 8
        for (int f = 0; f < FCC; ++f) acc += W2[f] * W1[f * HH + tid];
        wv[tid] = acc;
    }
    float cconst;
    {
        float acc = 0.0f;
        #pragma unroll 8
        for (int f = 0; f < FCC; ++f) acc += W2[f] * b1[f];
        cconst = acc + b2[0];
    }
    __syncthreads();

    const int r    = tid >> 1;    // hidden row this thread contributes to
    const int half = tid & 1;     // which half of the columns
    const int lane = tid & 63;
    const int wid  = tid >> 6;

    const float4* __restrict__ Wh4 = (const float4*)(W_hh + (size_t)r * HH + half * (HH / 2));
    const float4* __restrict__ Wi4 = (const float4*)(W_ih + r * FF + half * (FF / 2));

    int count = 0;

    for (int t = 0; t < len; ++t) {
        // stage x_t into LDS
        if (tid < FF) xt[tid] = x[((size_t)b * TT + t) * FF + tid];
        __syncthreads();

        // acc = (half of) W_hh[r,:] . h  +  (half of) W_ih[r,:] . x_t
        float acc = 0.0f;
        const float4* h4 = (const float4*)(h + half * (HH / 2));
        #pragma unroll 8
        for (int j = 0; j < HH / 8; ++j) {      // 64 float4s = 256 columns
            float4 wq = Wh4[j];
            float4 hq = h4[j];
            acc += wq.x * hq.x + wq.y * hq.y + wq.z * hq.z + wq.w * hq.w;
        }
        const float4* x4 = (const float4*)(xt + half * (FF / 2));
        #pragma unroll
        for (int j = 0; j < FF / 8; ++j) {      // 16 float4s = 64 columns
            float4 wq = Wi4[j];
            float4 xq = x4[j];
            acc += wq.x * xq.x + wq.y * xq.y + wq.z * xq.z + wq.w * xq.w;
        }
        acc += __shfl_xor(acc, 1);              // combine the two halves

        float hn = 0.0f;
        if (half == 0) hn = tanhf(acc + bias[r]);

        __syncthreads();                        // everyone done reading old h
        if (half == 0) h[r] = hn;
        __syncthreads();                        // h_t visible to all

        // score_t = h . wv + c  (wave shuffle reduce -> per-wave partials)
        float p = (tid < HH) ? h[tid] * wv[tid] : 0.0f;
        #pragma unroll
        for (int off = 32; off; off >>= 1) p += __shfl_xor(p, off);
        if (lane == 0) red[wid] = p;
        __syncthreads();
        if (tid == 0) {
            float s = cconst;
            #pragma unroll
            for (int w = 0; w < 16; ++w) s += red[w];
            if (s > 0.0f) ++count;
        }
        // red[] is only rewritten after two more barriers next iteration — safe.
    }

    __syncthreads();
    if (tid == 0) out[b] = (float)count;                 // outs [B,1]
    if (tid < HH) out[BB + b * HH + tid] = h[tid];       // h_final [B,H]
}

extern "C" void kernel_launch(void* const* d_in, const int* in_sizes, int n_in,
                              void* d_out, int out_size, void* d_ws, size_t ws_size,
                              hipStream_t stream) {
    const float* x      = (const float*)d_in[0];
    const int*   lens   = (const int*)d_in[1];
    const float* W_ih   = (const float*)d_in[2];
    const float* W_hh   = (const float*)d_in[3];
    const float* b_ih   = (const float*)d_in[4];
    const float* b_hh   = (const float*)d_in[5];
    const float* W1     = (const float*)d_in[6];
    const float* b1     = (const float*)d_in[7];
    const float* W2     = (const float*)d_in[8];
    const float* b2     = (const float*)d_in[9];
    float* out = (float*)d_out;

    rnn_encoder_kernel<<<dim3(BB), dim3(1024), 0, stream>>>(
        x, lens, W_ih, W_hh, b_ih, b_hh, W1, b1, W2, b2, out);
}

// Round 2
// 3757.038 us; speedup vs baseline: 15.4637x; 15.4637x over previous
//
#include <hip/hip_runtime.h>
#include <math.h>
#include <stdint.h>

#define BB 32
#define TT 2048
#define FF 128
#define HH 512
#define FCC 128
#define QW 8      // workgroups per batch
#define RPW 64    // hidden rows per WG
#define NTH 512   // threads per WG (8 waves -> VGPR budget 256, no spill)

// LDS pad: +4 floats per 64 -> chunk bases land on distinct bank groups
__device__ __forceinline__ int hpad(int i) { return i + ((i >> 6) << 2); }

__global__ void ws_zero(uint64_t* g) {
    g[(size_t)blockIdx.x * blockDim.x + threadIdx.x] = 0ull;
}

// grid = BB*QW = 256 blocks (1 per CU, all co-resident), 512 threads each.
// Thread (row=tid>>3, c=tid&7) owns rows grow=q*64+row restricted to cols
// [c*64, c*64+64) of W_hh (16 float4 in VGPRs) and cols [c*16,c*16+16) of
// W_ih/x. Per step: 80 reg-resident FMAs + 16 broadcast ds_read_b128, 3
// shfl_xor reduce, leaders publish tagged (step,value) u64 atomics; readers
// poll value+tag together (no fences needed), stage h into padded LDS.
__global__ __launch_bounds__(NTH, 1)
void rnn_seq(const float* __restrict__ x, const int* __restrict__ lengths,
             const float* __restrict__ W_ih, const float* __restrict__ W_hh,
             const float* __restrict__ b_ih, const float* __restrict__ b_hh,
             const float* __restrict__ W1, const float* __restrict__ b1,
             const float* __restrict__ W2, const float* __restrict__ b2,
             float* __restrict__ out, uint64_t* __restrict__ gbuf)
{
    const int blk = blockIdx.x;
    const int b   = blk >> 3;       // batch
    const int q   = blk & 7;        // row-quarter (eighth)
    const int tid = threadIdx.x;
    const int row = tid >> 3;       // 0..63
    const int c   = tid & 7;        // col chunk
    const int grow = q * RPW + row; // global hidden row
    const int len = lengths[b];

    __shared__ float hs[HH + (HH / 64) * 4];   // padded hidden state
    __shared__ float biass[RPW];
    __shared__ float red[2];

    // ---- weights into registers (one-time; ~1.25MB/WG total) ----
    float4 wr[16];
    {
        const float4* p = (const float4*)(W_hh + (size_t)grow * HH + c * 64);
        #pragma unroll
        for (int k = 0; k < 16; ++k) wr[k] = p[k];
    }
    float4 wi[4];
    {
        const float4* p = (const float4*)(W_ih + grow * FF + c * 16);
        #pragma unroll
        for (int k = 0; k < 4; ++k) wi[k] = p[k];
    }

    if (tid < RPW) biass[tid] = b_ih[q * RPW + tid] + b_hh[q * RPW + tid];
    if (tid < HH) hs[hpad(tid)] = 0.0f;

    // fused scorer vector wv = W2 @ W1 (cols 4*tid..4*tid+3) in registers
    float4 wvr = make_float4(0.f, 0.f, 0.f, 0.f);
    if (tid < 128) {
        for (int f = 0; f < FCC; ++f) {
            float w2 = W2[f];
            const float* w1 = W1 + f * HH + tid * 4;
            wvr.x += w2 * w1[0]; wvr.y += w2 * w1[1];
            wvr.z += w2 * w1[2]; wvr.w += w2 * w1[3];
        }
    }
    float cconst = 0.f;
    if (q == 0 && tid == 0) {
        float a = 0.f;
        for (int f = 0; f < FCC; ++f) a += W2[f] * b1[f];
        cconst = a + b2[0];
    }
    __syncthreads();

    const float* xb = x + (size_t)b * TT * FF;
    float4 rx[4];
    {
        const float4* p = (const float4*)(xb + c * 16);  // x_0
        #pragma unroll
        for (int k = 0; k < 4; ++k) rx[k] = p[k];
    }

    uint64_t* slot0 = gbuf + (size_t)b * HH;         // even steps
    uint64_t* slot1 = gbuf + (size_t)(BB + b) * HH;  // odd steps
    const int hbase = c * 68;                        // hpad(c*64)

    int count = 0;
    for (int i = 0; i < len; ++i) {
        // ---- matvec: acc = W_ih[grow,c-chunk].x_i + W_hh[grow,c-chunk].h_i
        float acc = 0.f;
        #pragma unroll
        for (int k = 0; k < 4; ++k) {
            float4 w = wi[k], v = rx[k];
            acc += w.x * v.x + w.y * v.y + w.z * v.z + w.w * v.w;
        }
        const float4* hq = (const float4*)(hs + hbase);
        #pragma unroll
        for (int k = 0; k < 16; ++k) {
            float4 w = wr[k], v = hq[k];
            acc += w.x * v.x + w.y * v.y + w.z * v.z + w.w * v.w;
        }
        // combine the 8 col-chunks (c is low 3 bits of lane)
        acc += __shfl_xor(acc, 1);
        acc += __shfl_xor(acc, 2);
        acc += __shfl_xor(acc, 4);

        uint64_t* sw = (i & 1) ? slot1 : slot0;
        if (c == 0) {
            float hnew = tanhf(acc + biass[row]);
            uint64_t pk = ((uint64_t)(uint32_t)(i + 1) << 32) |
                          (uint64_t)__float_as_uint(hnew);
            __hip_atomic_store(&sw[grow], pk, __ATOMIC_RELAXED, __HIP_MEMORY_SCOPE_AGENT);
        }
        // prefetch next x while the exchange is in flight
        if (i + 1 < len) {
            const float4* p = (const float4*)(xb + (size_t)(i + 1) * FF + c * 16);
            #pragma unroll
            for (int k = 0; k < 4; ++k) rx[k] = p[k];
        }
        __syncthreads();   // all waves done reading old hs

        if (tid < 128) {
            uint64_t u0, u1, u2, u3;
            const uint64_t tg = (uint64_t)(uint32_t)(i + 1);
            uint64_t* pr = sw + tid * 4;
            do {
                u0 = __hip_atomic_load(pr + 0, __ATOMIC_RELAXED, __HIP_MEMORY_SCOPE_AGENT);
                u1 = __hip_atomic_load(pr + 1, __ATOMIC_RELAXED, __HIP_MEMORY_SCOPE_AGENT);
                u2 = __hip_atomic_load(pr + 2, __ATOMIC_RELAXED, __HIP_MEMORY_SCOPE_AGENT);
                u3 = __hip_atomic_load(pr + 3, __ATOMIC_RELAXED, __HIP_MEMORY_SCOPE_AGENT);
            } while ((u0 >> 32) != tg || (u1 >> 32) != tg ||
                     (u2 >> 32) != tg || (u3 >> 32) != tg);
            float4 hv = make_float4(__uint_as_float((uint32_t)u0),
                                    __uint_as_float((uint32_t)u1),
                                    __uint_as_float((uint32_t)u2),
                                    __uint_as_float((uint32_t)u3));
            *(float4*)(hs + hpad(tid * 4)) = hv;
            // fused FC scorer on the fresh h (q0 only): score = h.wv + cconst
            if (q == 0) {
                float p2 = hv.x * wvr.x + hv.y * wvr.y + hv.z * wvr.z + hv.w * wvr.w;
                #pragma unroll
                for (int off = 32; off; off >>= 1) p2 += __shfl_xor(p2, off);
                if ((tid & 63) == 0) red[tid >> 6] = p2;
            }
        }
        __syncthreads();
        if (q == 0 && tid == 0) {
            float s = cconst + red[0] + red[1];
            if (s > 0.f) ++count;
        }
    }

    if (q == 0) {
        if (tid == 0) out[b] = (float)count;
        if (tid < HH) out[BB + b * HH + tid] = hs[hpad(tid)];
    }
}

extern "C" void kernel_launch(void* const* d_in, const int* in_sizes, int n_in,
                              void* d_out, int out_size, void* d_ws, size_t ws_size,
                              hipStream_t stream) {
    const float* x    = (const float*)d_in[0];
    const int*   lens = (const int*)d_in[1];
    const float* W_ih = (const float*)d_in[2];
    const float* W_hh = (const float*)d_in[3];
    const float* b_ih = (const float*)d_in[4];
    const float* b_hh = (const float*)d_in[5];
    const float* W1   = (const float*)d_in[6];
    const float* b1   = (const float*)d_in[7];
    const float* W2   = (const float*)d_in[8];
    const float* b2   = (const float*)d_in[9];
    float* out = (float*)d_out;
    uint64_t* gbuf = (uint64_t*)d_ws;   // 2 * 32 * 512 u64 = 256 KB

    // defense-in-depth: clear tags (0xAA poison already can't alias a step tag)
    ws_zero<<<dim3((2 * BB * HH) / 256), dim3(256), 0, stream>>>(gbuf);
    rnn_seq<<<dim3(BB * QW), dim3(NTH), 0, stream>>>(
        x, lens, W_ih, W_hh, b_ih, b_hh, W1, b1, W2, b2, out, gbuf);
}